// Round 14
// baseline (133.428 us; speedup 1.0000x reference)
//
#include <hip/hip_runtime.h>
#include <hip/hip_bf16.h>

// Problem constants
#define NATOMS 4096     // B*N = 8*512
#define DESC_ 2048
#define MAXTILES 67     // sum ceil(cnt_t/64) <= 64+3

typedef short short8 __attribute__((ext_vector_type(8)));
typedef float f32x4 __attribute__((ext_vector_type(4)));
typedef unsigned short u16x8 __attribute__((ext_vector_type(8)));
typedef unsigned short u16x4 __attribute__((ext_vector_type(4)));
typedef unsigned short u16;

__device__ __forceinline__ float fast_tanh(float x) {
    // tanh(x) = 1 - 2/(exp2(x*2/ln2)+1); exp2f -> single v_exp_f32
    float e = exp2f(x * 2.885390081777927f);
    return 1.0f - 2.0f * __builtin_amdgcn_rcpf(e + 1.0f);
}

__device__ __forceinline__ float bf2f(u16 h) {
    union { unsigned int u; float f; } v; v.u = ((unsigned int)h) << 16;
    return v.f;
}
// round-to-nearest bf16 (single-plane data)
__device__ __forceinline__ u16 f2bf_rn(float f) {
    union { float f; unsigned int u; } v; v.f = f;
    unsigned int r = v.u + 0x7fffu + ((v.u >> 16) & 1u);
    return (u16)(r >> 16);
}
// truncation split: x ~= hi + lo to ~2^-15 rel, 3 VALU ops
__device__ __forceinline__ void f2bf_split(float x, u16& hi, u16& lo) {
    union { float f; unsigned int u; } v; v.f = x;
    unsigned int hb = v.u & 0xffff0000u;
    hi = (u16)(hb >> 16);
    union { unsigned int u; float f; } w; w.u = hb;
    union { float f; unsigned int u; } z; z.f = x - w.f;
    lo = (u16)(z.u >> 16);
}

__device__ __forceinline__ void conv4(const float* __restrict__ src,
                                      u16* __restrict__ dh, u16* __restrict__ dl,
                                      int idx)
{
    float4 v = *(const float4*)(src + idx);
    u16x4 oh, ol;
    u16 h, l;
    f2bf_split(v.x, h, l); oh[0] = h; ol[0] = l;
    f2bf_split(v.y, h, l); oh[1] = h; ol[1] = l;
    f2bf_split(v.z, h, l); oh[2] = h; ol[2] = l;
    f2bf_split(v.w, h, l); oh[3] = h; ol[3] = l;
    *(u16x4*)(dh + idx) = oh;
    *(u16x4*)(dl + idx) = ol;
}

// ---------------------------------------------------------------------------
// Fused prep: block 0 = counting sort (perm/meta); blocks 1.. = weight splits.
// ---------------------------------------------------------------------------
__global__ __launch_bounds__(256) void prep_kernel(
    const int* __restrict__ types, int* __restrict__ perm, int* __restrict__ meta,
    const float* __restrict__ Wf1, u16* __restrict__ F1h, u16* __restrict__ F1l,
    const float* __restrict__ Wf2, u16* __restrict__ F2h, u16* __restrict__ F2l,
    const float* __restrict__ Wt0, u16* __restrict__ W0h, u16* __restrict__ W0l,
    const float* __restrict__ Wt1, u16* __restrict__ W1h, u16* __restrict__ W1l,
    const float* __restrict__ Wt2, u16* __restrict__ W2h, u16* __restrict__ W2l)
{
    __shared__ int cnt[256 * 4];
    __shared__ int tot[4];
    __shared__ int tstart[4];
    int b = blockIdx.x;
    int tid = threadIdx.x;
    if (b == 0) {
        int base = tid * 16;
        int c0 = 0, c1 = 0, c2 = 0, c3 = 0;
        for (int i = 0; i < 16; ++i) {
            int t = types[base + i];
            c0 += (t == 0); c1 += (t == 1); c2 += (t == 2); c3 += (t == 3);
        }
        cnt[tid * 4 + 0] = c0; cnt[tid * 4 + 1] = c1;
        cnt[tid * 4 + 2] = c2; cnt[tid * 4 + 3] = c3;
        __syncthreads();
        if (tid < 4) {
            int run = 0;
            for (int th = 0; th < 256; ++th) {
                int v = cnt[th * 4 + tid];
                cnt[th * 4 + tid] = run;
                run += v;
            }
            tot[tid] = run;
        }
        __syncthreads();
        if (tid == 0) {
            int run = 0, nt = 0;
            for (int t = 0; t < 4; ++t) { tstart[t] = run; run += tot[t]; }
            for (int t = 0; t < 4; ++t) {
                int cT = tot[t];
                for (int off = 0; off < cT; off += 64) {
                    meta[1 + nt * 3 + 0] = t;
                    meta[1 + nt * 3 + 1] = tstart[t] + off;
                    meta[1 + nt * 3 + 2] = (cT - off < 64) ? (cT - off) : 64;
                    nt++;
                }
            }
            meta[0] = nt;
        }
        __syncthreads();
        for (int i = 0; i < 16; ++i) {
            int idx = base + i;
            int t = types[idx];
            perm[tstart[t] + cnt[tid * 4 + t]++] = idx;
        }
        return;
    }
    b -= 1;
    const float* src; u16 *dh, *dl; int n, base;
    if (b < 2048)      { src = Wt0; dh = W0h; dl = W0l; n = 2097152; base = b; }
    else if (b < 2304) { src = Wt1; dh = W1h; dl = W1l; n = 262144;  base = b - 2048; }
    else if (b < 2560) { src = Wt2; dh = W2h; dl = W2l; n = 262144;  base = b - 2304; }
    else if (b < 2568) { src = Wf1; dh = F1h; dl = F1l; n = 8192;    base = b - 2560; }
    else               { src = Wf2; dh = F2h; dl = F2l; n = 32768;   base = b - 2568; }
    int idx = (base * 256 + tid) * 4;
    if (idx < n) conv4(src, dh, dl, idx);
}

// ---------------------------------------------------------------------------
// Filter net + descriptor per atom, split-bf16 MFMA (round-11 structure).
// Weight fragments (b1/b2/biases, dependent only on t) hoisted to kernel top
// so their L2 latency hides under L0/L1 compute. D written single-plane (RN).
// LDS = 40960 B -> 4 blocks/CU.
// ---------------------------------------------------------------------------
__global__ __launch_bounds__(256) void filter_kernel(
    const float* __restrict__ sym, const int* __restrict__ types,
    const int* __restrict__ perm,
    const float* __restrict__ Wf0, const float* __restrict__ bf0,
    const u16* __restrict__ F1h, const u16* __restrict__ F1l,
    const float* __restrict__ bf1,
    const u16* __restrict__ F2h, const u16* __restrict__ F2l,
    const float* __restrict__ bf2,
    u16* __restrict__ Dh)
{
    __shared__ char lds[40960] __attribute__((aligned(16)));
    float* Rl  = (float*)lds;            // [128][4]
    u16*   G1h = (u16*)(lds + 2048);     // [128][72]
    u16*   G1l = (u16*)(lds + 20480);    // [128][72]
    float* RGl = (float*)(lds + 38912);  // [4][128]

    int p = blockIdx.x;
    int tid = threadIdx.x;
    int atom = perm[p];
    int t = __builtin_amdgcn_readfirstlane(types[atom]);
    int lane = tid & 63;
    int wv   = tid >> 6;
    int kg   = lane >> 4;
    int l15  = lane & 15;

    // ---- HOISTED weight-fragment loads (depend only on t) ----------------
    short8 b1h[4], b1l[4];
    float  bias1[4];
    #pragma unroll
    for (int nt = 0; nt < 4; ++nt) {
        int off = t * 2048 + (nt * 16 + l15) * 32 + kg * 8;
        b1h[nt] = *(const short8*)(F1h + off);
        b1l[nt] = *(const short8*)(F1l + off);
        bias1[nt] = bf1[t * 64 + nt * 16 + l15];
    }
    short8 b2h[2][2], b2l[2][2];
    float  bias2[2];
    #pragma unroll
    for (int ntl = 0; ntl < 2; ++ntl) {
        int nt = wv * 2 + ntl;
        bias2[ntl] = bf2[t * 128 + nt * 16 + l15];
        #pragma unroll
        for (int ks = 0; ks < 2; ++ks) {
            int off = t * 8192 + (nt * 16 + l15) * 64 + ks * 32 + kg * 8;
            b2h[ntl][ks] = *(const short8*)(F2h + off);
            b2l[ntl][ks] = *(const short8*)(F2l + off);
        }
    }

    ((float2*)Rl)[tid] = ((const float2*)(sym + (size_t)atom * 512))[tid];

    // ---- L0 in registers (A-fragment layout) + L1 MFMA -> G1 hi/lo -------
    {
        const float4* w0p = (const float4*)(Wf0 + t * 32 + kg * 8);
        float4 w04 = w0p[0], w14 = w0p[1];
        const float4* b0p = (const float4*)(bf0 + t * 32 + kg * 8);
        float4 b04 = b0p[0], b14 = b0p[1];

        short8 ah[2], al[2];
        #pragma unroll
        for (int mi = 0; mi < 2; ++mi) {
            int s = (wv * 2 + mi) * 16 + l15;
            float sv = sym[(size_t)atom * 512 + s * 4];
            float g[8];
            g[0] = fast_tanh(sv * w04.x + b04.x);
            g[1] = fast_tanh(sv * w04.y + b04.y);
            g[2] = fast_tanh(sv * w04.z + b04.z);
            g[3] = fast_tanh(sv * w04.w + b04.w);
            g[4] = fast_tanh(sv * w14.x + b14.x);
            g[5] = fast_tanh(sv * w14.y + b14.y);
            g[6] = fast_tanh(sv * w14.z + b14.z);
            g[7] = fast_tanh(sv * w14.w + b14.w);
            #pragma unroll
            for (int j = 0; j < 8; ++j) {
                u16 h, l; f2bf_split(g[j], h, l);
                ah[mi][j] = (short)h; al[mi][j] = (short)l;
            }
        }

        #pragma unroll
        for (int mi = 0; mi < 2; ++mi) {
            int mt = wv * 2 + mi;
            #pragma unroll
            for (int nt = 0; nt < 4; ++nt) {
                f32x4 acc = {0.f, 0.f, 0.f, 0.f};
                acc = __builtin_amdgcn_mfma_f32_16x16x32_bf16(ah[mi], b1h[nt], acc, 0, 0, 0);
                acc = __builtin_amdgcn_mfma_f32_16x16x32_bf16(ah[mi], b1l[nt], acc, 0, 0, 0);
                acc = __builtin_amdgcn_mfma_f32_16x16x32_bf16(al[mi], b1h[nt], acc, 0, 0, 0);
                int rowb = mt * 16 + kg * 4;
                #pragma unroll
                for (int r = 0; r < 4; ++r) {
                    u16 h, l;
                    f2bf_split(fast_tanh(acc[r] + bias1[nt]), h, l);
                    G1h[(rowb + r) * 72 + nt * 16 + l15] = h;
                    G1l[(rowb + r) * 72 + nt * 16 + l15] = l;
                }
            }
        }
    }
    __syncthreads();

    // ---- L2 (K=64) fused with RG contraction -----------------------------
    {
        float rg[4][2];
        #pragma unroll
        for (int d = 0; d < 4; ++d) { rg[d][0] = 0.f; rg[d][1] = 0.f; }

        #pragma unroll 2
        for (int mt = 0; mt < 8; ++mt) {
            int i0 = (mt * 16 + l15) * 72 + kg * 8;
            short8 a0h = *(const short8*)&G1h[i0];
            short8 a0l = *(const short8*)&G1l[i0];
            short8 a1h = *(const short8*)&G1h[i0 + 32];
            short8 a1l = *(const short8*)&G1l[i0 + 32];
            f32x4 acc0 = {0.f,0.f,0.f,0.f}, acc1 = {0.f,0.f,0.f,0.f};
            acc0 = __builtin_amdgcn_mfma_f32_16x16x32_bf16(a0h, b2h[0][0], acc0, 0,0,0);
            acc0 = __builtin_amdgcn_mfma_f32_16x16x32_bf16(a0h, b2l[0][0], acc0, 0,0,0);
            acc0 = __builtin_amdgcn_mfma_f32_16x16x32_bf16(a0l, b2h[0][0], acc0, 0,0,0);
            acc0 = __builtin_amdgcn_mfma_f32_16x16x32_bf16(a1h, b2h[0][1], acc0, 0,0,0);
            acc0 = __builtin_amdgcn_mfma_f32_16x16x32_bf16(a1h, b2l[0][1], acc0, 0,0,0);
            acc0 = __builtin_amdgcn_mfma_f32_16x16x32_bf16(a1l, b2h[0][1], acc0, 0,0,0);
            acc1 = __builtin_amdgcn_mfma_f32_16x16x32_bf16(a0h, b2h[1][0], acc1, 0,0,0);
            acc1 = __builtin_amdgcn_mfma_f32_16x16x32_bf16(a0h, b2l[1][0], acc1, 0,0,0);
            acc1 = __builtin_amdgcn_mfma_f32_16x16x32_bf16(a0l, b2h[1][0], acc1, 0,0,0);
            acc1 = __builtin_amdgcn_mfma_f32_16x16x32_bf16(a1h, b2h[1][1], acc1, 0,0,0);
            acc1 = __builtin_amdgcn_mfma_f32_16x16x32_bf16(a1h, b2l[1][1], acc1, 0,0,0);
            acc1 = __builtin_amdgcn_mfma_f32_16x16x32_bf16(a1l, b2h[1][1], acc1, 0,0,0);
            int rowb = mt * 16 + kg * 4;
            #pragma unroll
            for (int r = 0; r < 4; ++r) {
                float4 R4 = *(const float4*)&Rl[(rowb + r) * 4];
                float g0 = fast_tanh(acc0[r] + bias2[0]);
                float g1 = fast_tanh(acc1[r] + bias2[1]);
                rg[0][0] += R4.x * g0; rg[1][0] += R4.y * g0;
                rg[2][0] += R4.z * g0; rg[3][0] += R4.w * g0;
                rg[0][1] += R4.x * g1; rg[1][1] += R4.y * g1;
                rg[2][1] += R4.z * g1; rg[3][1] += R4.w * g1;
            }
        }
        #pragma unroll
        for (int off = 16; off < 64; off <<= 1) {
            #pragma unroll
            for (int d = 0; d < 4; ++d) {
                rg[d][0] += __shfl_xor(rg[d][0], off, 64);
                rg[d][1] += __shfl_xor(rg[d][1], off, 64);
            }
        }
        if (kg == 0) {
            #pragma unroll
            for (int d = 0; d < 4; ++d) {
                RGl[d * 128 + wv * 32 + l15]      = rg[d][0];
                RGl[d * 128 + wv * 32 + 16 + l15] = rg[d][1];
            }
        }
    }
    __syncthreads();

    // ---- GRRG -> D single bf16 plane (RN) --------------------------------
    {
        int m = tid >> 1;
        int ab = (tid & 1) * 8;
        float rm0 = RGl[0 * 128 + m], rm1 = RGl[1 * 128 + m];
        float rm2 = RGl[2 * 128 + m], rm3 = RGl[3 * 128 + m];
        u16x8 oh;
        #pragma unroll
        for (int q = 0; q < 8; ++q) {
            int a = ab + q;
            float v = rm0 * RGl[0 * 128 + a] + rm1 * RGl[1 * 128 + a]
                    + rm2 * RGl[2 * 128 + a] + rm3 * RGl[3 * 128 + a];
            oh[q] = f2bf_rn(v);
        }
        *(u16x8*)(Dh + (size_t)p * DESC_ + m * 16 + ab) = oh;
    }
}

// ---------------------------------------------------------------------------
// fit L0, split-K=4. Block = 64a x 64h x 512k. grid = ntiles*16 (~4 blk/CU).
// A (single-plane D) staged in LDS (9 KB); W hi/lo read direct from global.
// acc += A*Bh + A*Bl (2 MFMAs). Writes f32 partials (deterministic).
// ---------------------------------------------------------------------------
__global__ __launch_bounds__(256) void fit0_partial(
    const u16* __restrict__ inh,
    const u16* __restrict__ Wh,  const u16* __restrict__ Wl,
    float* __restrict__ part, const int* __restrict__ meta)
{
    __shared__ char lds[9216] __attribute__((aligned(16)));
    u16* Ath = (u16*)lds;             // [64][72]

    int ntiles = meta[0];
    int b = blockIdx.x;
    int tile = b >> 4;
    if (tile >= ntiles) return;
    int hq  = (b >> 2) & 3;
    int ksp = b & 3;
    int t   = __builtin_amdgcn_readfirstlane(meta[1 + tile * 3 + 0]);
    int p0  = meta[1 + tile * 3 + 1];
    int cnt = meta[1 + tile * 3 + 2];
    int h0b = hq * 64;

    int tid = threadIdx.x;
    int lane = tid & 63;
    int wv   = tid >> 6;
    int kg   = lane >> 4;
    int l15  = lane & 15;

    int srow = tid >> 2;
    int skc  = (tid & 3) * 16;
    int agrow = p0 + srow; if (agrow > NATOMS - 1) agrow = NATOMS - 1;
    const u16* arow_h = inh + (size_t)agrow * 2048;
    int hmy = h0b + wv * 16 + l15;
    const u16* brow_h = Wh + ((size_t)t * 256 + hmy) * 2048;
    const u16* brow_l = Wl + ((size_t)t * 256 + hmy) * 2048;

    f32x4 acc[4];
    #pragma unroll
    for (int mt = 0; mt < 4; ++mt) acc[mt] = (f32x4){0.f, 0.f, 0.f, 0.f};

    int kbase = ksp * 512;
    for (int k0 = kbase; k0 < kbase + 512; k0 += 64) {
        u16x8 a0 = *(const u16x8*)(arow_h + k0 + skc);
        u16x8 a1 = *(const u16x8*)(arow_h + k0 + skc + 8);
        __syncthreads();   // previous chunk's LDS reads done
        int si = srow * 72 + skc;
        *(u16x8*)&Ath[si]     = a0;
        *(u16x8*)&Ath[si + 8] = a1;
        __syncthreads();

        #pragma unroll
        for (int ks = 0; ks < 2; ++ks) {
            short8 bh = *(const short8*)(brow_h + k0 + ks * 32 + kg * 8);
            short8 bl = *(const short8*)(brow_l + k0 + ks * 32 + kg * 8);
            #pragma unroll
            for (int mt = 0; mt < 4; ++mt) {
                int ai = (mt * 16 + l15) * 72 + ks * 32 + kg * 8;
                short8 ah = *(const short8*)&Ath[ai];
                acc[mt] = __builtin_amdgcn_mfma_f32_16x16x32_bf16(ah, bh, acc[mt], 0, 0, 0);
                acc[mt] = __builtin_amdgcn_mfma_f32_16x16x32_bf16(ah, bl, acc[mt], 0, 0, 0);
            }
        }
    }

    float* pdst = part + (size_t)ksp * (NATOMS * 256);
    #pragma unroll
    for (int mt = 0; mt < 4; ++mt) {
        #pragma unroll
        for (int r = 0; r < 4; ++r) {
            int al = mt * 16 + kg * 4 + r;
            if (al < cnt)
                pdst[(size_t)(p0 + al) * 256 + hmy] = acc[mt][r];
        }
    }
}

// ---------------------------------------------------------------------------
// fit L0 epilogue: sum 4 partials + bias + tanh -> h0 single bf16 plane (RN).
// grid covers exactly NATOMS*256 at 4/thread -> 1024 blocks.
// ---------------------------------------------------------------------------
__global__ __launch_bounds__(256) void fit0_epi(
    const float* __restrict__ part, const float* __restrict__ bias,
    const int* __restrict__ perm, const int* __restrict__ types,
    u16* __restrict__ outh)
{
    const int PN = NATOMS * 256;
    int idx = (blockIdx.x * 256 + threadIdx.x) * 4;
    if (idx >= PN) return;
    int p = idx >> 8;
    int t = types[perm[p]];
    float4 s0 = *(const float4*)(part + idx);
    float4 s1 = *(const float4*)(part + PN + idx);
    float4 s2 = *(const float4*)(part + 2 * PN + idx);
    float4 s3 = *(const float4*)(part + 3 * PN + idx);
    float4 bv = *(const float4*)(bias + t * 256 + (idx & 255));
    u16x4 oh;
    oh[0] = f2bf_rn(fast_tanh(s0.x + s1.x + s2.x + s3.x + bv.x));
    oh[1] = f2bf_rn(fast_tanh(s0.y + s1.y + s2.y + s3.y + bv.y));
    oh[2] = f2bf_rn(fast_tanh(s0.z + s1.z + s2.z + s3.z + bv.z));
    oh[3] = f2bf_rn(fast_tanh(s0.w + s1.w + s2.w + s3.w + bv.w));
    *(u16x4*)(outh + idx) = oh;
}

// ---------------------------------------------------------------------------
// MFMA fitting layer (K=256). Block = 64a x 64h, grid = MAXTILES*4.
// A (single-plane bf16) staged in LDS (9 KB); W hi/lo read DIRECT from global
// (B rows are wave-private — LDS staging was pure overhead). 2 MFMAs/pair.
// ---------------------------------------------------------------------------
__global__ __launch_bounds__(256) void fit_mfma(
    const u16* __restrict__ inh,
    const u16* __restrict__ Wh,  const u16* __restrict__ Wl,
    const float* __restrict__ bias,
    u16* __restrict__ outh,
    int K, const int* __restrict__ meta)
{
    __shared__ char lds[9216] __attribute__((aligned(16)));
    u16* Ath = (u16*)lds;             // [64][72]

    int ntiles = meta[0];
    int tile = blockIdx.x >> 2;
    if (tile >= ntiles) return;
    int hq  = blockIdx.x & 3;
    int t   = __builtin_amdgcn_readfirstlane(meta[1 + tile * 3 + 0]);
    int p0  = meta[1 + tile * 3 + 1];
    int cnt = meta[1 + tile * 3 + 2];
    int h0b = hq * 64;

    int tid = threadIdx.x;
    int lane = tid & 63;
    int wv   = tid >> 6;
    int kg   = lane >> 4;
    int l15  = lane & 15;

    int srow = tid >> 2;
    int skc  = (tid & 3) * 16;
    int agrow = p0 + srow; if (agrow > NATOMS - 1) agrow = NATOMS - 1;
    const u16* arow_h = inh + (size_t)agrow * K;
    int hmy = h0b + wv * 16 + l15;
    const u16* brow_h = Wh + ((size_t)t * 256 + hmy) * K;
    const u16* brow_l = Wl + ((size_t)t * 256 + hmy) * K;

    f32x4 acc[4];
    #pragma unroll
    for (int mt = 0; mt < 4; ++mt) acc[mt] = (f32x4){0.f, 0.f, 0.f, 0.f};

    for (int k0 = 0; k0 < K; k0 += 64) {
        u16x8 a0 = *(const u16x8*)(arow_h + k0 + skc);
        u16x8 a1 = *(const u16x8*)(arow_h + k0 + skc + 8);
        __syncthreads();
        int si = srow * 72 + skc;
        *(u16x8*)&Ath[si]     = a0;
        *(u16x8*)&Ath[si + 8] = a1;
        __syncthreads();

        #pragma unroll
        for (int ks = 0; ks < 2; ++ks) {
            short8 bh = *(const short8*)(brow_h + k0 + ks * 32 + kg * 8);
            short8 bl = *(const short8*)(brow_l + k0 + ks * 32 + kg * 8);
            #pragma unroll
            for (int mt = 0; mt < 4; ++mt) {
                int ai = (mt * 16 + l15) * 72 + ks * 32 + kg * 8;
                short8 ah = *(const short8*)&Ath[ai];
                acc[mt] = __builtin_amdgcn_mfma_f32_16x16x32_bf16(ah, bh, acc[mt], 0, 0, 0);
                acc[mt] = __builtin_amdgcn_mfma_f32_16x16x32_bf16(ah, bl, acc[mt], 0, 0, 0);
            }
        }
    }

    int h = h0b + wv * 16 + l15;
    float b = bias[t * 256 + h];
    #pragma unroll
    for (int mt = 0; mt < 4; ++mt) {
        #pragma unroll
        for (int r = 0; r < 4; ++r) {
            int al = mt * 16 + kg * 4 + r;
            if (al < cnt) {
                float v = fast_tanh(acc[mt][r] + b);
                size_t o = (size_t)(p0 + al) * 256 + h;
                outh[o] = f2bf_rn(v);
            }
        }
    }
}

// ---------------------------------------------------------------------------
// Per-atom energy: e2[atom] = h2 . Wo[t] + bo[t]. One wave per sorted pos.
// No atomics — deterministic.
// ---------------------------------------------------------------------------
__global__ __launch_bounds__(256) void final_kernel(
    const u16* __restrict__ h2h,
    const int* __restrict__ perm, const int* __restrict__ types,
    const float* __restrict__ Wo, const float* __restrict__ bo,
    float* __restrict__ e2)
{
    int tid = threadIdx.x;
    int wv = tid >> 6;
    int lane = tid & 63;
    int p = blockIdx.x * 4 + wv;
    int atom = perm[p];
    int t = types[atom];
    const u16* hh = h2h + (size_t)p * 256;
    float e = 0.f;
    #pragma unroll
    for (int r = 0; r < 4; ++r) {
        int h = r * 64 + lane;
        e += bf2f(hh[h]) * Wo[t * 256 + h];
    }
    #pragma unroll
    for (int off = 32; off > 0; off >>= 1)
        e += __shfl_xor(e, off, 64);
    if (lane == 0) e2[atom] = e + bo[t];
}

// ---------------------------------------------------------------------------
// Deterministic per-batch reduction: out[b] = sum_{n<512} e2[b*512+n].
// ---------------------------------------------------------------------------
__global__ __launch_bounds__(256) void reduce_kernel(
    const float* __restrict__ e2, float* __restrict__ out)
{
    __shared__ float s[256];
    int b = blockIdx.x;
    int tid = threadIdx.x;
    s[tid] = e2[b * 512 + tid] + e2[b * 512 + 256 + tid];
    __syncthreads();
    #pragma unroll
    for (int off = 128; off > 0; off >>= 1) {
        if (tid < off) s[tid] += s[tid + off];
        __syncthreads();
    }
    if (tid == 0) out[b] = s[0];
}

// ---------------------------------------------------------------------------
extern "C" void kernel_launch(void* const* d_in, const int* in_sizes, int n_in,
                              void* d_out, int out_size, void* d_ws, size_t ws_size,
                              hipStream_t stream) {
    const float* sym = (const float*)d_in[0];
    const int*   types = (const int*)d_in[1];
    const float* Wf0 = (const float*)d_in[2];
    const float* bf0 = (const float*)d_in[3];
    const float* Wf1 = (const float*)d_in[4];
    const float* bf1 = (const float*)d_in[5];
    const float* Wf2 = (const float*)d_in[6];
    const float* bf2 = (const float*)d_in[7];
    const float* Wt0 = (const float*)d_in[8];
    const float* bt0 = (const float*)d_in[9];
    const float* Wt1 = (const float*)d_in[10];
    const float* bt1 = (const float*)d_in[11];
    const float* Wt2 = (const float*)d_in[12];
    const float* bt2 = (const float*)d_in[13];
    const float* Wo  = (const float*)d_in[14];
    const float* bo  = (const float*)d_in[15];
    float* out = (float*)d_out;

    char* ws = (char*)d_ws;
    const size_t MB = 1024 * 1024;
    int*  meta = (int*)ws;                          // 1 KB
    int*  perm = (int*)(ws + 1024);                 // 16 KB
    char* base = ws + 32768;
    // Dh live: filter -> fit0_partial. Region reused afterwards:
    u16*  Dh   = (u16*)(base);                      // 16 MB
    u16*  h1h  = (u16*)(base);                      // 2 MB  (alias Dh, L1 output)
    u16*  h2h  = (u16*)(base + 4 * MB);             // 2 MB
    float* e2  = (float*)(base + 8 * MB);           // 16 KB
    u16*  h0h  = (u16*)(base + 32 * MB);            // 2 MB
    u16*  W0h  = (u16*)(base + 36 * MB);            // 4 MB
    u16*  W0l  = (u16*)(base + 40 * MB);            // 4 MB
    u16*  W1h  = (u16*)(base + 44 * MB);            // 512 KB
    u16*  W1l  = (u16*)(base + 44 * MB + 512 * 1024);
    u16*  W2h  = (u16*)(base + 45 * MB);
    u16*  W2l  = (u16*)(base + 45 * MB + 512 * 1024);
    u16*  F1h  = (u16*)(base + 46 * MB);            // 16 KB each
    u16*  F1l  = (u16*)(base + 46 * MB + 16 * 1024);
    u16*  F2h  = (u16*)(base + 46 * MB + 32 * 1024);  // 64 KB each
    u16*  F2l  = (u16*)(base + 46 * MB + 96 * 1024);
    float* part = (float*)(base + 47 * MB);         // 16 MB (4 x 4 MB f32)
    // total ws usage: 32 KB + 63 MB

    prep_kernel<<<2601, 256, 0, stream>>>(types, perm, meta,
                                          Wf1, F1h, F1l, Wf2, F2h, F2l,
                                          Wt0, W0h, W0l, Wt1, W1h, W1l,
                                          Wt2, W2h, W2l);

    filter_kernel<<<NATOMS, 256, 0, stream>>>(sym, types, perm,
                                              Wf0, bf0, F1h, F1l, bf1,
                                              F2h, F2l, bf2, Dh);

    fit0_partial<<<MAXTILES * 16, 256, 0, stream>>>(Dh, W0h, W0l, part, meta);
    fit0_epi<<<NATOMS / 4, 256, 0, stream>>>(part, bt0, perm, types, h0h);

    fit_mfma<<<MAXTILES * 4, 256, 0, stream>>>(h0h, W1h, W1l, bt1,
                                               h1h, 256, meta);
    fit_mfma<<<MAXTILES * 4, 256, 0, stream>>>(h1h, W2h, W2l, bt2,
                                               h2h, 256, meta);

    final_kernel<<<NATOMS / 4, 256, 0, stream>>>(h2h, perm, types, Wo, bo, e2);
    reduce_kernel<<<8, 256, 0, stream>>>(e2, out);
}

// Round 16
// 127.510 us; speedup vs baseline: 1.0464x; 1.0464x over previous
//
#include <hip/hip_runtime.h>
#include <hip/hip_bf16.h>

// Problem constants
#define NATOMS 4096     // B*N = 8*512
#define DESC_ 2048
#define MAXTILES 67     // sum ceil(cnt_t/64) <= 64+3

typedef short short8 __attribute__((ext_vector_type(8)));
typedef float f32x4 __attribute__((ext_vector_type(4)));
typedef unsigned short u16x8 __attribute__((ext_vector_type(8)));
typedef unsigned short u16x4 __attribute__((ext_vector_type(4)));
typedef unsigned short u16;

__device__ __forceinline__ float fast_tanh(float x) {
    float e = __expf(2.0f * x);
    return 1.0f - 2.0f * __builtin_amdgcn_rcpf(e + 1.0f);
}

__device__ __forceinline__ float bf2f(u16 h) {
    union { unsigned int u; float f; } v; v.u = ((unsigned int)h) << 16;
    return v.f;
}
// round-to-nearest bf16 (single-plane data)
__device__ __forceinline__ u16 f2bf_rn(float f) {
    union { float f; unsigned int u; } v; v.f = f;
    unsigned int r = v.u + 0x7fffu + ((v.u >> 16) & 1u);
    return (u16)(r >> 16);
}
// truncation split: x ~= hi + lo to ~2^-15 rel, 3 VALU ops
__device__ __forceinline__ void f2bf_split(float x, u16& hi, u16& lo) {
    union { float f; unsigned int u; } v; v.f = x;
    unsigned int hb = v.u & 0xffff0000u;
    hi = (u16)(hb >> 16);
    union { unsigned int u; float f; } w; w.u = hb;
    union { float f; unsigned int u; } z; z.f = x - w.f;
    lo = (u16)(z.u >> 16);
}

__device__ __forceinline__ void conv4(const float* __restrict__ src,
                                      u16* __restrict__ dh, u16* __restrict__ dl,
                                      int idx)
{
    float4 v = *(const float4*)(src + idx);
    u16x4 oh, ol;
    u16 h, l;
    f2bf_split(v.x, h, l); oh[0] = h; ol[0] = l;
    f2bf_split(v.y, h, l); oh[1] = h; ol[1] = l;
    f2bf_split(v.z, h, l); oh[2] = h; ol[2] = l;
    f2bf_split(v.w, h, l); oh[3] = h; ol[3] = l;
    *(u16x4*)(dh + idx) = oh;
    *(u16x4*)(dl + idx) = ol;
}

// ---------------------------------------------------------------------------
// Fused prep: block 0 = counting sort (perm/meta); blocks 1.. = weight splits.
// ---------------------------------------------------------------------------
__global__ __launch_bounds__(256) void prep_kernel(
    const int* __restrict__ types, int* __restrict__ perm, int* __restrict__ meta,
    const float* __restrict__ Wf1, u16* __restrict__ F1h, u16* __restrict__ F1l,
    const float* __restrict__ Wf2, u16* __restrict__ F2h, u16* __restrict__ F2l,
    const float* __restrict__ Wt0, u16* __restrict__ W0h, u16* __restrict__ W0l,
    const float* __restrict__ Wt1, u16* __restrict__ W1h, u16* __restrict__ W1l,
    const float* __restrict__ Wt2, u16* __restrict__ W2h, u16* __restrict__ W2l)
{
    __shared__ int cnt[256 * 4];
    __shared__ int tot[4];
    __shared__ int tstart[4];
    int b = blockIdx.x;
    int tid = threadIdx.x;
    if (b == 0) {
        int base = tid * 16;
        int c0 = 0, c1 = 0, c2 = 0, c3 = 0;
        for (int i = 0; i < 16; ++i) {
            int t = types[base + i];
            c0 += (t == 0); c1 += (t == 1); c2 += (t == 2); c3 += (t == 3);
        }
        cnt[tid * 4 + 0] = c0; cnt[tid * 4 + 1] = c1;
        cnt[tid * 4 + 2] = c2; cnt[tid * 4 + 3] = c3;
        __syncthreads();
        if (tid < 4) {
            int run = 0;
            for (int th = 0; th < 256; ++th) {
                int v = cnt[th * 4 + tid];
                cnt[th * 4 + tid] = run;
                run += v;
            }
            tot[tid] = run;
        }
        __syncthreads();
        if (tid == 0) {
            int run = 0, nt = 0;
            for (int t = 0; t < 4; ++t) { tstart[t] = run; run += tot[t]; }
            for (int t = 0; t < 4; ++t) {
                int cT = tot[t];
                for (int off = 0; off < cT; off += 64) {
                    meta[1 + nt * 3 + 0] = t;
                    meta[1 + nt * 3 + 1] = tstart[t] + off;
                    meta[1 + nt * 3 + 2] = (cT - off < 64) ? (cT - off) : 64;
                    nt++;
                }
            }
            meta[0] = nt;
        }
        __syncthreads();
        for (int i = 0; i < 16; ++i) {
            int idx = base + i;
            int t = types[idx];
            perm[tstart[t] + cnt[tid * 4 + t]++] = idx;
        }
        return;
    }
    b -= 1;
    const float* src; u16 *dh, *dl; int n, base;
    if (b < 2048)      { src = Wt0; dh = W0h; dl = W0l; n = 2097152; base = b; }
    else if (b < 2304) { src = Wt1; dh = W1h; dl = W1l; n = 262144;  base = b - 2048; }
    else if (b < 2560) { src = Wt2; dh = W2h; dl = W2l; n = 262144;  base = b - 2304; }
    else if (b < 2568) { src = Wf1; dh = F1h; dl = F1l; n = 8192;    base = b - 2560; }
    else               { src = Wf2; dh = F2h; dl = F2l; n = 32768;   base = b - 2568; }
    int idx = (base * 256 + tid) * 4;
    if (idx < n) conv4(src, dh, dl, idx);
}

// ---------------------------------------------------------------------------
// Filter net + descriptor per atom, split-bf16 MFMA (round-9 proven version).
// D written as SINGLE bf16 plane (RN). LDS = 40960 B -> 4 blocks/CU.
// ---------------------------------------------------------------------------
__global__ __launch_bounds__(256) void filter_kernel(
    const float* __restrict__ sym, const int* __restrict__ types,
    const int* __restrict__ perm,
    const float* __restrict__ Wf0, const float* __restrict__ bf0,
    const u16* __restrict__ F1h, const u16* __restrict__ F1l,
    const float* __restrict__ bf1,
    const u16* __restrict__ F2h, const u16* __restrict__ F2l,
    const float* __restrict__ bf2,
    u16* __restrict__ Dh)
{
    __shared__ char lds[40960] __attribute__((aligned(16)));
    float* Rl  = (float*)lds;            // [128][4]
    u16*   G1h = (u16*)(lds + 2048);     // [128][72]
    u16*   G1l = (u16*)(lds + 20480);    // [128][72]
    float* RGl = (float*)(lds + 38912);  // [4][128]

    int p = blockIdx.x;
    int tid = threadIdx.x;
    int atom = perm[p];
    int t = __builtin_amdgcn_readfirstlane(types[atom]);
    int lane = tid & 63;
    int wv   = tid >> 6;
    int kg   = lane >> 4;
    int l15  = lane & 15;

    ((float2*)Rl)[tid] = ((const float2*)(sym + (size_t)atom * 512))[tid];

    // L0 in registers (A-fragment layout) + L1 MFMA -> G1 hi/lo
    {
        const float4* w0p = (const float4*)(Wf0 + t * 32 + kg * 8);
        float4 w04 = w0p[0], w14 = w0p[1];
        const float4* b0p = (const float4*)(bf0 + t * 32 + kg * 8);
        float4 b04 = b0p[0], b14 = b0p[1];

        short8 ah[2], al[2];
        #pragma unroll
        for (int mi = 0; mi < 2; ++mi) {
            int s = (wv * 2 + mi) * 16 + l15;
            float sv = sym[(size_t)atom * 512 + s * 4];
            float g[8];
            g[0] = fast_tanh(sv * w04.x + b04.x);
            g[1] = fast_tanh(sv * w04.y + b04.y);
            g[2] = fast_tanh(sv * w04.z + b04.z);
            g[3] = fast_tanh(sv * w04.w + b04.w);
            g[4] = fast_tanh(sv * w14.x + b14.x);
            g[5] = fast_tanh(sv * w14.y + b14.y);
            g[6] = fast_tanh(sv * w14.z + b14.z);
            g[7] = fast_tanh(sv * w14.w + b14.w);
            #pragma unroll
            for (int j = 0; j < 8; ++j) {
                u16 h, l; f2bf_split(g[j], h, l);
                ah[mi][j] = (short)h; al[mi][j] = (short)l;
            }
        }

        short8 b1h[4], b1l[4];
        float  bias1[4];
        #pragma unroll
        for (int nt = 0; nt < 4; ++nt) {
            int off = t * 2048 + (nt * 16 + l15) * 32 + kg * 8;
            b1h[nt] = *(const short8*)(F1h + off);
            b1l[nt] = *(const short8*)(F1l + off);
            bias1[nt] = bf1[t * 64 + nt * 16 + l15];
        }
        #pragma unroll
        for (int mi = 0; mi < 2; ++mi) {
            int mt = wv * 2 + mi;
            #pragma unroll
            for (int nt = 0; nt < 4; ++nt) {
                f32x4 acc = {0.f, 0.f, 0.f, 0.f};
                acc = __builtin_amdgcn_mfma_f32_16x16x32_bf16(ah[mi], b1h[nt], acc, 0, 0, 0);
                acc = __builtin_amdgcn_mfma_f32_16x16x32_bf16(ah[mi], b1l[nt], acc, 0, 0, 0);
                acc = __builtin_amdgcn_mfma_f32_16x16x32_bf16(al[mi], b1h[nt], acc, 0, 0, 0);
                int rowb = mt * 16 + kg * 4;
                #pragma unroll
                for (int r = 0; r < 4; ++r) {
                    u16 h, l;
                    f2bf_split(fast_tanh(acc[r] + bias1[nt]), h, l);
                    G1h[(rowb + r) * 72 + nt * 16 + l15] = h;
                    G1l[(rowb + r) * 72 + nt * 16 + l15] = l;
                }
            }
        }
    }
    __syncthreads();

    // L2 (K=64) fused with RG contraction
    {
        short8 b2h[2][2], b2l[2][2];
        float  bias2[2];
        #pragma unroll
        for (int ntl = 0; ntl < 2; ++ntl) {
            int nt = wv * 2 + ntl;
            bias2[ntl] = bf2[t * 128 + nt * 16 + l15];
            #pragma unroll
            for (int ks = 0; ks < 2; ++ks) {
                int off = t * 8192 + (nt * 16 + l15) * 64 + ks * 32 + kg * 8;
                b2h[ntl][ks] = *(const short8*)(F2h + off);
                b2l[ntl][ks] = *(const short8*)(F2l + off);
            }
        }
        float rg[4][2];
        #pragma unroll
        for (int d = 0; d < 4; ++d) { rg[d][0] = 0.f; rg[d][1] = 0.f; }

        #pragma unroll 2
        for (int mt = 0; mt < 8; ++mt) {
            int i0 = (mt * 16 + l15) * 72 + kg * 8;
            short8 a0h = *(const short8*)&G1h[i0];
            short8 a0l = *(const short8*)&G1l[i0];
            short8 a1h = *(const short8*)&G1h[i0 + 32];
            short8 a1l = *(const short8*)&G1l[i0 + 32];
            f32x4 acc0 = {0.f,0.f,0.f,0.f}, acc1 = {0.f,0.f,0.f,0.f};
            acc0 = __builtin_amdgcn_mfma_f32_16x16x32_bf16(a0h, b2h[0][0], acc0, 0,0,0);
            acc0 = __builtin_amdgcn_mfma_f32_16x16x32_bf16(a0h, b2l[0][0], acc0, 0,0,0);
            acc0 = __builtin_amdgcn_mfma_f32_16x16x32_bf16(a0l, b2h[0][0], acc0, 0,0,0);
            acc0 = __builtin_amdgcn_mfma_f32_16x16x32_bf16(a1h, b2h[0][1], acc0, 0,0,0);
            acc0 = __builtin_amdgcn_mfma_f32_16x16x32_bf16(a1h, b2l[0][1], acc0, 0,0,0);
            acc0 = __builtin_amdgcn_mfma_f32_16x16x32_bf16(a1l, b2h[0][1], acc0, 0,0,0);
            acc1 = __builtin_amdgcn_mfma_f32_16x16x32_bf16(a0h, b2h[1][0], acc1, 0,0,0);
            acc1 = __builtin_amdgcn_mfma_f32_16x16x32_bf16(a0h, b2l[1][0], acc1, 0,0,0);
            acc1 = __builtin_amdgcn_mfma_f32_16x16x32_bf16(a0l, b2h[1][0], acc1, 0,0,0);
            acc1 = __builtin_amdgcn_mfma_f32_16x16x32_bf16(a1h, b2h[1][1], acc1, 0,0,0);
            acc1 = __builtin_amdgcn_mfma_f32_16x16x32_bf16(a1h, b2l[1][1], acc1, 0,0,0);
            acc1 = __builtin_amdgcn_mfma_f32_16x16x32_bf16(a1l, b2h[1][1], acc1, 0,0,0);
            int rowb = mt * 16 + kg * 4;
            #pragma unroll
            for (int r = 0; r < 4; ++r) {
                float4 R4 = *(const float4*)&Rl[(rowb + r) * 4];
                float g0 = fast_tanh(acc0[r] + bias2[0]);
                float g1 = fast_tanh(acc1[r] + bias2[1]);
                rg[0][0] += R4.x * g0; rg[1][0] += R4.y * g0;
                rg[2][0] += R4.z * g0; rg[3][0] += R4.w * g0;
                rg[0][1] += R4.x * g1; rg[1][1] += R4.y * g1;
                rg[2][1] += R4.z * g1; rg[3][1] += R4.w * g1;
            }
        }
        #pragma unroll
        for (int off = 16; off < 64; off <<= 1) {
            #pragma unroll
            for (int d = 0; d < 4; ++d) {
                rg[d][0] += __shfl_xor(rg[d][0], off, 64);
                rg[d][1] += __shfl_xor(rg[d][1], off, 64);
            }
        }
        if (kg == 0) {
            #pragma unroll
            for (int d = 0; d < 4; ++d) {
                RGl[d * 128 + wv * 32 + l15]      = rg[d][0];
                RGl[d * 128 + wv * 32 + 16 + l15] = rg[d][1];
            }
        }
    }
    __syncthreads();

    // GRRG -> D single bf16 plane (RN)
    {
        int m = tid >> 1;
        int ab = (tid & 1) * 8;
        float rm0 = RGl[0 * 128 + m], rm1 = RGl[1 * 128 + m];
        float rm2 = RGl[2 * 128 + m], rm3 = RGl[3 * 128 + m];
        u16x8 oh;
        #pragma unroll
        for (int q = 0; q < 8; ++q) {
            int a = ab + q;
            float v = rm0 * RGl[0 * 128 + a] + rm1 * RGl[1 * 128 + a]
                    + rm2 * RGl[2 * 128 + a] + rm3 * RGl[3 * 128 + a];
            oh[q] = f2bf_rn(v);
        }
        *(u16x8*)(Dh + (size_t)p * DESC_ + m * 16 + ab) = oh;
    }
}

// ---------------------------------------------------------------------------
// fit L0, split-K=4. Block = 64a x 64h x 512k. grid = ntiles*16 (~4 blk/CU).
// A (single-plane D) staged in LDS (9 KB); W hi/lo read direct from global.
// acc += A*Bh + A*Bl (2 MFMAs). Writes f32 partials (deterministic).
// ---------------------------------------------------------------------------
__global__ __launch_bounds__(256) void fit0_partial(
    const u16* __restrict__ inh,
    const u16* __restrict__ Wh,  const u16* __restrict__ Wl,
    float* __restrict__ part, const int* __restrict__ meta)
{
    __shared__ char lds[9216] __attribute__((aligned(16)));
    u16* Ath = (u16*)lds;             // [64][72]

    int ntiles = meta[0];
    int b = blockIdx.x;
    int tile = b >> 4;
    if (tile >= ntiles) return;
    int hq  = (b >> 2) & 3;
    int ksp = b & 3;
    int t   = __builtin_amdgcn_readfirstlane(meta[1 + tile * 3 + 0]);
    int p0  = meta[1 + tile * 3 + 1];
    int cnt = meta[1 + tile * 3 + 2];
    int h0b = hq * 64;

    int tid = threadIdx.x;
    int lane = tid & 63;
    int wv   = tid >> 6;
    int kg   = lane >> 4;
    int l15  = lane & 15;

    int srow = tid >> 2;
    int skc  = (tid & 3) * 16;
    int agrow = p0 + srow; if (agrow > NATOMS - 1) agrow = NATOMS - 1;
    const u16* arow_h = inh + (size_t)agrow * 2048;
    int hmy = h0b + wv * 16 + l15;
    const u16* brow_h = Wh + ((size_t)t * 256 + hmy) * 2048;
    const u16* brow_l = Wl + ((size_t)t * 256 + hmy) * 2048;

    f32x4 acc[4];
    #pragma unroll
    for (int mt = 0; mt < 4; ++mt) acc[mt] = (f32x4){0.f, 0.f, 0.f, 0.f};

    int kbase = ksp * 512;
    for (int k0 = kbase; k0 < kbase + 512; k0 += 64) {
        u16x8 a0 = *(const u16x8*)(arow_h + k0 + skc);
        u16x8 a1 = *(const u16x8*)(arow_h + k0 + skc + 8);
        __syncthreads();   // previous chunk's LDS reads done
        int si = srow * 72 + skc;
        *(u16x8*)&Ath[si]     = a0;
        *(u16x8*)&Ath[si + 8] = a1;
        __syncthreads();

        #pragma unroll
        for (int ks = 0; ks < 2; ++ks) {
            short8 bh = *(const short8*)(brow_h + k0 + ks * 32 + kg * 8);
            short8 bl = *(const short8*)(brow_l + k0 + ks * 32 + kg * 8);
            #pragma unroll
            for (int mt = 0; mt < 4; ++mt) {
                int ai = (mt * 16 + l15) * 72 + ks * 32 + kg * 8;
                short8 ah = *(const short8*)&Ath[ai];
                acc[mt] = __builtin_amdgcn_mfma_f32_16x16x32_bf16(ah, bh, acc[mt], 0, 0, 0);
                acc[mt] = __builtin_amdgcn_mfma_f32_16x16x32_bf16(ah, bl, acc[mt], 0, 0, 0);
            }
        }
    }

    float* pdst = part + (size_t)ksp * (NATOMS * 256);
    #pragma unroll
    for (int mt = 0; mt < 4; ++mt) {
        #pragma unroll
        for (int r = 0; r < 4; ++r) {
            int al = mt * 16 + kg * 4 + r;
            if (al < cnt)
                pdst[(size_t)(p0 + al) * 256 + hmy] = acc[mt][r];
        }
    }
}

// ---------------------------------------------------------------------------
// fit L0 epilogue: sum 4 partials + bias + tanh -> h0 single bf16 plane (RN).
// grid covers exactly NATOMS*256 at 4/thread -> 1024 blocks.
// ---------------------------------------------------------------------------
__global__ __launch_bounds__(256) void fit0_epi(
    const float* __restrict__ part, const float* __restrict__ bias,
    const int* __restrict__ perm, const int* __restrict__ types,
    u16* __restrict__ outh)
{
    const int PN = NATOMS * 256;
    int idx = (blockIdx.x * 256 + threadIdx.x) * 4;
    if (idx >= PN) return;
    int p = idx >> 8;
    int t = types[perm[p]];
    float4 s0 = *(const float4*)(part + idx);
    float4 s1 = *(const float4*)(part + PN + idx);
    float4 s2 = *(const float4*)(part + 2 * PN + idx);
    float4 s3 = *(const float4*)(part + 3 * PN + idx);
    float4 bv = *(const float4*)(bias + t * 256 + (idx & 255));
    u16x4 oh;
    oh[0] = f2bf_rn(fast_tanh(s0.x + s1.x + s2.x + s3.x + bv.x));
    oh[1] = f2bf_rn(fast_tanh(s0.y + s1.y + s2.y + s3.y + bv.y));
    oh[2] = f2bf_rn(fast_tanh(s0.z + s1.z + s2.z + s3.z + bv.z));
    oh[3] = f2bf_rn(fast_tanh(s0.w + s1.w + s2.w + s3.w + bv.w));
    *(u16x4*)(outh + idx) = oh;
}

// ---------------------------------------------------------------------------
// MFMA fitting layer (K=256). Block = 64a x 64h, grid = MAXTILES*4.
// A is single-plane bf16 activation; W is hi/lo. 2 MFMAs per pair.
// LDS 27648 B. Writes single bf16 plane (RN). No atomics.
// ---------------------------------------------------------------------------
__global__ __launch_bounds__(256) void fit_mfma(
    const u16* __restrict__ inh,
    const u16* __restrict__ Wh,  const u16* __restrict__ Wl,
    const float* __restrict__ bias,
    u16* __restrict__ outh,
    int K, const int* __restrict__ meta)
{
    __shared__ char lds[27648] __attribute__((aligned(16)));
    u16* Ath = (u16*)lds;             // [64][72]
    u16* Bth = (u16*)(lds + 9216);    // [64][72]
    u16* Btl = (u16*)(lds + 18432);   // [64][72]

    int ntiles = meta[0];
    int tile = blockIdx.x >> 2;
    if (tile >= ntiles) return;
    int hq  = blockIdx.x & 3;
    int t   = __builtin_amdgcn_readfirstlane(meta[1 + tile * 3 + 0]);
    int p0  = meta[1 + tile * 3 + 1];
    int cnt = meta[1 + tile * 3 + 2];
    int h0b = hq * 64;

    int tid = threadIdx.x;
    int lane = tid & 63;
    int wv   = tid >> 6;
    int kg   = lane >> 4;
    int l15  = lane & 15;

    int srow = tid >> 2;
    int skc  = (tid & 3) * 16;
    int agrow = p0 + srow; if (agrow > NATOMS - 1) agrow = NATOMS - 1;
    const u16* arow_h = inh + (size_t)agrow * K;
    const u16* brow_h = Wh + ((size_t)t * 256 + h0b + srow) * K;
    const u16* brow_l = Wl + ((size_t)t * 256 + h0b + srow) * K;

    f32x4 acc[4];
    #pragma unroll
    for (int mt = 0; mt < 4; ++mt) acc[mt] = (f32x4){0.f, 0.f, 0.f, 0.f};

    for (int k0 = 0; k0 < K; k0 += 64) {
        u16x8 a0 = *(const u16x8*)(arow_h + k0 + skc);
        u16x8 a1 = *(const u16x8*)(arow_h + k0 + skc + 8);
        u16x8 b0 = *(const u16x8*)(brow_h + k0 + skc);
        u16x8 b1 = *(const u16x8*)(brow_h + k0 + skc + 8);
        u16x8 b2 = *(const u16x8*)(brow_l + k0 + skc);
        u16x8 b3 = *(const u16x8*)(brow_l + k0 + skc + 8);
        __syncthreads();
        int si = srow * 72 + skc;
        *(u16x8*)&Ath[si]     = a0;
        *(u16x8*)&Ath[si + 8] = a1;
        *(u16x8*)&Bth[si]     = b0;
        *(u16x8*)&Bth[si + 8] = b1;
        *(u16x8*)&Btl[si]     = b2;
        *(u16x8*)&Btl[si + 8] = b3;
        __syncthreads();

        #pragma unroll
        for (int ks = 0; ks < 2; ++ks) {
            int bi = (wv * 16 + l15) * 72 + ks * 32 + kg * 8;
            short8 bh = *(const short8*)&Bth[bi];
            short8 bl = *(const short8*)&Btl[bi];
            #pragma unroll
            for (int mt = 0; mt < 4; ++mt) {
                int ai = (mt * 16 + l15) * 72 + ks * 32 + kg * 8;
                short8 ah = *(const short8*)&Ath[ai];
                acc[mt] = __builtin_amdgcn_mfma_f32_16x16x32_bf16(ah, bh, acc[mt], 0, 0, 0);
                acc[mt] = __builtin_amdgcn_mfma_f32_16x16x32_bf16(ah, bl, acc[mt], 0, 0, 0);
            }
        }
    }

    int h = h0b + wv * 16 + l15;
    float b = bias[t * 256 + h];
    #pragma unroll
    for (int mt = 0; mt < 4; ++mt) {
        #pragma unroll
        for (int r = 0; r < 4; ++r) {
            int al = mt * 16 + kg * 4 + r;
            if (al < cnt) {
                float v = fast_tanh(acc[mt][r] + b);
                size_t o = (size_t)(p0 + al) * 256 + h;
                outh[o] = f2bf_rn(v);
            }
        }
    }
}

// ---------------------------------------------------------------------------
// Per-atom energy: e2[atom] = h2 . Wo[t] + bo[t]. One wave per sorted pos.
// No atomics — deterministic.
// ---------------------------------------------------------------------------
__global__ __launch_bounds__(256) void final_kernel(
    const u16* __restrict__ h2h,
    const int* __restrict__ perm, const int* __restrict__ types,
    const float* __restrict__ Wo, const float* __restrict__ bo,
    float* __restrict__ e2)
{
    int tid = threadIdx.x;
    int wv = tid >> 6;
    int lane = tid & 63;
    int p = blockIdx.x * 4 + wv;
    int atom = perm[p];
    int t = types[atom];
    const u16* hh = h2h + (size_t)p * 256;
    float e = 0.f;
    #pragma unroll
    for (int r = 0; r < 4; ++r) {
        int h = r * 64 + lane;
        e += bf2f(hh[h]) * Wo[t * 256 + h];
    }
    #pragma unroll
    for (int off = 32; off > 0; off >>= 1)
        e += __shfl_xor(e, off, 64);
    if (lane == 0) e2[atom] = e + bo[t];
}

// ---------------------------------------------------------------------------
// Deterministic per-batch reduction: out[b] = sum_{n<512} e2[b*512+n].
// ---------------------------------------------------------------------------
__global__ __launch_bounds__(256) void reduce_kernel(
    const float* __restrict__ e2, float* __restrict__ out)
{
    __shared__ float s[256];
    int b = blockIdx.x;
    int tid = threadIdx.x;
    s[tid] = e2[b * 512 + tid] + e2[b * 512 + 256 + tid];
    __syncthreads();
    #pragma unroll
    for (int off = 128; off > 0; off >>= 1) {
        if (tid < off) s[tid] += s[tid + off];
        __syncthreads();
    }
    if (tid == 0) out[b] = s[0];
}

// ---------------------------------------------------------------------------
extern "C" void kernel_launch(void* const* d_in, const int* in_sizes, int n_in,
                              void* d_out, int out_size, void* d_ws, size_t ws_size,
                              hipStream_t stream) {
    const float* sym = (const float*)d_in[0];
    const int*   types = (const int*)d_in[1];
    const float* Wf0 = (const float*)d_in[2];
    const float* bf0 = (const float*)d_in[3];
    const float* Wf1 = (const float*)d_in[4];
    const float* bf1 = (const float*)d_in[5];
    const float* Wf2 = (const float*)d_in[6];
    const float* bf2 = (const float*)d_in[7];
    const float* Wt0 = (const float*)d_in[8];
    const float* bt0 = (const float*)d_in[9];
    const float* Wt1 = (const float*)d_in[10];
    const float* bt1 = (const float*)d_in[11];
    const float* Wt2 = (const float*)d_in[12];
    const float* bt2 = (const float*)d_in[13];
    const float* Wo  = (const float*)d_in[14];
    const float* bo  = (const float*)d_in[15];
    float* out = (float*)d_out;

    char* ws = (char*)d_ws;
    const size_t MB = 1024 * 1024;
    int*  meta = (int*)ws;                          // 1 KB
    int*  perm = (int*)(ws + 1024);                 // 16 KB
    char* base = ws + 32768;
    // Dh live: filter -> fit0_partial. Region reused afterwards:
    u16*  Dh   = (u16*)(base);                      // 16 MB
    u16*  h1h  = (u16*)(base);                      // 2 MB  (alias Dh, L1 output)
    u16*  h2h  = (u16*)(base + 4 * MB);             // 2 MB
    float* e2  = (float*)(base + 8 * MB);           // 16 KB
    u16*  h0h  = (u16*)(base + 32 * MB);            // 2 MB
    u16*  W0h  = (u16*)(base + 36 * MB);            // 4 MB
    u16*  W0l  = (u16*)(base + 40 * MB);            // 4 MB
    u16*  W1h  = (u16*)(base + 44 * MB);            // 512 KB
    u16*  W1l  = (u16*)(base + 44 * MB + 512 * 1024);
    u16*  W2h  = (u16*)(base + 45 * MB);
    u16*  W2l  = (u16*)(base + 45 * MB + 512 * 1024);
    u16*  F1h  = (u16*)(base + 46 * MB);            // 16 KB each
    u16*  F1l  = (u16*)(base + 46 * MB + 16 * 1024);
    u16*  F2h  = (u16*)(base + 46 * MB + 32 * 1024);  // 64 KB each
    u16*  F2l  = (u16*)(base + 46 * MB + 96 * 1024);
    float* part = (float*)(base + 47 * MB);         // 16 MB (4 x 4 MB f32)
    // total ws usage: 32 KB + 63 MB

    prep_kernel<<<2601, 256, 0, stream>>>(types, perm, meta,
                                          Wf1, F1h, F1l, Wf2, F2h, F2l,
                                          Wt0, W0h, W0l, Wt1, W1h, W1l,
                                          Wt2, W2h, W2l);

    filter_kernel<<<NATOMS, 256, 0, stream>>>(sym, types, perm,
                                              Wf0, bf0, F1h, F1l, bf1,
                                              F2h, F2l, bf2, Dh);

    fit0_partial<<<MAXTILES * 16, 256, 0, stream>>>(Dh, W0h, W0l, part, meta);
    fit0_epi<<<NATOMS / 4, 256, 0, stream>>>(part, bt0, perm, types, h0h);

    fit_mfma<<<MAXTILES * 4, 256, 0, stream>>>(h0h, W1h, W1l, bt1,
                                               h1h, 256, meta);
    fit_mfma<<<MAXTILES * 4, 256, 0, stream>>>(h1h, W2h, W2l, bt2,
                                               h2h, 256, meta);

    final_kernel<<<NATOMS / 4, 256, 0, stream>>>(h2h, perm, types, Wo, bo, e2);
    reduce_kernel<<<8, 256, 0, stream>>>(e2, out);
}